// Round 13
// baseline (288.950 us; speedup 1.0000x reference)
//
#include <hip/hip_runtime.h>
#include <hip/hip_bf16.h>

#define N_NODES 8192
#define N_IN 512
#define N_OUT 512

typedef __bf16 bf16;
typedef __bf16 bf16x4 __attribute__((ext_vector_type(4)));
typedef __bf16 bf16x8 __attribute__((ext_vector_type(8)));
typedef float f32x4 __attribute__((ext_vector_type(4)));

__device__ __forceinline__ void gload16(const void* g, void* l) {
  __builtin_amdgcn_global_load_lds((const __attribute__((address_space(1))) void*)g,
                                   (__attribute__((address_space(3))) void*)l, 16, 0, 0);
}

#define WAITVM(N) asm volatile("s_waitcnt vmcnt(" #N ")" ::: "memory")
#define BAR() do { asm volatile("" ::: "memory"); __builtin_amdgcn_s_barrier(); \
                   asm volatile("" ::: "memory"); } while (0)
#define SCHED0() __builtin_amdgcn_sched_barrier(0)
#define LGKM0() asm volatile("s_waitcnt lgkmcnt(0)" ::: "memory")

// ---- kernel 1: column partial sums + fp32->bf16 convert, +I folded into diagonal ----
// MEASUREMENT ROUND: launched TWICE (idempotent). Marginal total vs R7's
// 196.7us = this kernel's true duration (rocprof top-5 is masked by fills).
__global__ __launch_bounds__(256) void k_colsum_cvt(const float* __restrict__ adj,
                                                    bf16* __restrict__ adjb,
                                                    float* __restrict__ partial) {
  const int tid  = threadIdx.x;
  const int col0 = blockIdx.x * 1024 + tid * 4;
  const int row0 = blockIdx.y * 64;
  float s0 = 0.f, s1 = 0.f, s2 = 0.f, s3 = 0.f;
#pragma unroll 4
  for (int r = 0; r < 64; ++r) {
    float4 v = *reinterpret_cast<const float4*>(adj + (size_t)(row0 + r) * N_NODES + col0);
    s0 += v.x; s1 += v.y; s2 += v.z; s3 += v.w;   // degree uses ORIGINAL adj (+1 via init)
    const int dq = row0 + r - col0;               // fold identity: adjb[i][i] = adj[i][i]+1
    if ((unsigned)dq < 4u) reinterpret_cast<float*>(&v)[dq] += 1.0f;
    bf16x4 o = { (bf16)v.x, (bf16)v.y, (bf16)v.z, (bf16)v.w };
    *reinterpret_cast<bf16x4*>(adjb + (size_t)(row0 + r) * N_NODES + col0) = o;
  }
  float4 ps = { s0, s1, s2, s3 };
  *reinterpret_cast<float4*>(partial + (size_t)blockIdx.y * N_NODES + col0) = ps;
}

// ---- kernel 2 (merged): blocks 0..31 -> d[j]=rsqrt(1+colsum); 32..287 -> W cvt ----
__global__ __launch_bounds__(256) void k_dvec_wcvt(const float* __restrict__ partial,
                                                   float* __restrict__ dv,
                                                   const float* __restrict__ W,
                                                   bf16* __restrict__ Wb) {
  const int b = blockIdx.x;
  const int tid = threadIdx.x;
  if (b < 32) {
    const int j = b * 256 + tid;
    float s = 1.0f;
#pragma unroll 8
    for (int p = 0; p < 128; ++p) s += partial[(size_t)p * N_NODES + j];
    dv[j] = rsqrtf(s);
  } else {
    const int i = ((b - 32) * 256 + tid) * 4;
    float4 v = *reinterpret_cast<const float4*>(W + i);
    bf16x4 o = { (bf16)v.x, (bf16)v.y, (bf16)v.z, (bf16)v.w };
    *reinterpret_cast<bf16x4*>(Wb + i) = o;
  }
}

// ---- kernel 3: Hst[k][j] = d[j]*H[j][k]  (transpose+scale, bf16; B^T layout for GEMM1) ----
__global__ __launch_bounds__(256) void k_hst(const float* __restrict__ H,
                                             const float* __restrict__ dv,
                                             bf16* __restrict__ Hst) {
  __shared__ float t[64][65];
  const int tid = threadIdx.x;
  const int j0 = blockIdx.x * 64;
  const int k0 = blockIdx.y * 64;
  const int rr = tid >> 4;
  const int cc = (tid & 15) * 4;
#pragma unroll
  for (int p = 0; p < 4; ++p) {
    const int r = p * 16 + rr;
    const float d = dv[j0 + r];
    float4 v = *reinterpret_cast<const float4*>(H + (size_t)(j0 + r) * N_IN + k0 + cc);
    t[r][cc + 0] = v.x * d; t[r][cc + 1] = v.y * d;
    t[r][cc + 2] = v.z * d; t[r][cc + 3] = v.w * d;
  }
  __syncthreads();
#pragma unroll
  for (int p = 0; p < 4; ++p) {
    const int kr = p * 16 + rr;
    bf16x4 o = { (bf16)t[cc + 0][kr], (bf16)t[cc + 1][kr],
                 (bf16)t[cc + 2][kr], (bf16)t[cc + 3][kr] };
    *reinterpret_cast<bf16x4*>(Hst + (size_t)(k0 + kr) * N_NODES + j0 + cc) = o;
  }
}

// ============ gemm1: 8-phase 256x256 machine (R7, measured ~59us/1165TF) ============
template<int KDIM, int NSPLIT>
__global__ __launch_bounds__(512, 2) void k_gemm256(
    const bf16* __restrict__ A, const bf16* __restrict__ B, bf16* __restrict__ P) {
  constexpr int KSEG = KDIM / NSPLIT;          // 2048
  constexpr int NT = KSEG / 64;                // 32 K-tiles
  constexpr int NIT = NT / 2;                  // 16 iters
  constexpr int NBLK = 64 * NSPLIT;            // 256
  __shared__ __attribute__((aligned(128))) char lds[2 * 65536];

  const int bid = blockIdx.x;
  const int l = (bid & 7) * (NBLK / 8) + (bid >> 3);
  const int split = l / 64;
  const int rem = l % 64;
  const int bm0 = (rem >> 1) * 256;
  const int bn0 = (rem & 1) * 256;

  const int tid = threadIdx.x;
  const int lane = tid & 63;
  const int wid = tid >> 6;
  const int wr = wid >> 2;
  const int wc = wid & 3;

  const int srow = tid >> 3;
  const int sslot = (tid & 7) ^ (srow & 7);
  const size_t koff = (size_t)split * KSEG;
  const int wuni = wid * 1024;

  auto GA = [&](int k, int h, int buf) {
    const bf16* g = A + (size_t)(bm0 + h * 128 + srow) * KDIM + koff + (size_t)k * 64 + sslot * 8;
    char* d = lds + buf * 65536 + h * 16384 + wuni;
    gload16(g, d);
    gload16(g + (size_t)64 * KDIM, d + 8192);
  };
  auto GB = [&](int k, int h, int buf) {
    const bf16* g = B + (size_t)(bn0 + h * 128 + srow) * KDIM + koff + (size_t)k * 64 + sslot * 8;
    char* d = lds + buf * 65536 + 32768 + h * 16384 + wuni;
    gload16(g, d);
    gload16(g + (size_t)64 * KDIM, d + 8192);
  };

  const int frow = lane & 15;
  const int fk = lane >> 4;
  const int e7 = lane & 7;
  const int sb0 = ((fk) ^ e7) << 4;
  const int sb1 = ((4 + fk) ^ e7) << 4;
  const int aBase = wr * 16384 + frow * 128;
  const int bBase = 32768 + (wc >> 1) * 16384 + ((wc & 1) * 64 + frow) * 128;

  f32x4 acc[8][4] = {};
  bf16x8 av[2][4], bv0[2][2], bv1[2][2];

#define LDA(BUF, MH)                                                          \
  do {                                                                        \
    const char* lb_ = lds + (BUF) * 65536;                                    \
    _Pragma("unroll") for (int m = 0; m < 4; ++m) {                           \
      av[0][m] = *(const bf16x8*)(lb_ + aBase + ((MH) * 4 + m) * 2048 + sb0); \
      av[1][m] = *(const bf16x8*)(lb_ + aBase + ((MH) * 4 + m) * 2048 + sb1); \
    }                                                                         \
  } while (0)
#define LDB(BUF, NH, BV)                                                      \
  do {                                                                        \
    const char* lb_ = lds + (BUF) * 65536;                                    \
    _Pragma("unroll") for (int n = 0; n < 2; ++n) {                           \
      BV[0][n] = *(const bf16x8*)(lb_ + bBase + ((NH) * 2 + n) * 2048 + sb0); \
      BV[1][n] = *(const bf16x8*)(lb_ + bBase + ((NH) * 2 + n) * 2048 + sb1); \
    }                                                                         \
  } while (0)
#define MFMA16(MH, NH, BV)                                                    \
  do {                                                                        \
    _Pragma("unroll") for (int kk = 0; kk < 2; ++kk)                          \
    _Pragma("unroll") for (int m = 0; m < 4; ++m)                             \
    _Pragma("unroll") for (int n = 0; n < 2; ++n)                             \
      acc[(MH) * 4 + m][(NH) * 2 + n] = __builtin_amdgcn_mfma_f32_16x16x32_bf16( \
          av[kk][m], BV[kk][n], acc[(MH) * 4 + m][(NH) * 2 + n], 0, 0, 0);    \
  } while (0)

#define PH_OPEN()  do { SCHED0(); __builtin_amdgcn_s_barrier(); LGKM0(); SCHED0(); \
                        __builtin_amdgcn_s_setprio(1); } while (0)
#define PH_CLOSE() do { __builtin_amdgcn_s_setprio(0); SCHED0(); \
                        __builtin_amdgcn_s_barrier(); SCHED0(); } while (0)
#define PH_CLOSE_F(WV) do { __builtin_amdgcn_s_setprio(0); SCHED0(); WV; \
                            __builtin_amdgcn_s_barrier(); SCHED0(); } while (0)

  GB(0, 0, 0); GB(0, 1, 0); GA(0, 0, 0); GA(0, 1, 0);
  GB(1, 0, 1); GB(1, 1, 1);
  WAITVM(4);
  BAR();

#pragma unroll 1
  for (int i = 0; i < NIT; ++i) {
    const int t = 2 * i;
    const bool s2 = (t + 2 < NT);
    const bool s3 = (t + 3 < NT);
    LDA(0, 0); LDB(0, 0, bv0);
    GA(t + 1, 0, 1);
    PH_OPEN(); MFMA16(0, 0, bv0); PH_CLOSE();
    LDB(0, 1, bv1);
    GA(t + 1, 1, 1);
    PH_OPEN(); MFMA16(0, 1, bv1); PH_CLOSE();
    LDA(0, 1);
    if (s2) GB(t + 2, 0, 0);
    PH_OPEN(); MFMA16(1, 1, bv1); PH_CLOSE();
    if (s2) GB(t + 2, 1, 0);
    PH_OPEN(); MFMA16(1, 0, bv0);
    if (s2) { PH_CLOSE_F(WAITVM(4)); } else { PH_CLOSE_F(WAITVM(0)); }
    LDA(1, 0); LDB(1, 0, bv0);
    if (s2) GA(t + 2, 0, 0);
    PH_OPEN(); MFMA16(0, 0, bv0); PH_CLOSE();
    LDB(1, 1, bv1);
    if (s2) GA(t + 2, 1, 0);
    PH_OPEN(); MFMA16(0, 1, bv1); PH_CLOSE();
    LDA(1, 1);
    if (s3) GB(t + 3, 0, 1);
    PH_OPEN(); MFMA16(1, 1, bv1); PH_CLOSE();
    if (s3) GB(t + 3, 1, 1);
    PH_OPEN(); MFMA16(1, 0, bv0);
    if (s3) { PH_CLOSE_F(WAITVM(4)); } else { PH_CLOSE_F(WAITVM(0)); }
  }
#undef LDA
#undef LDB
#undef MFMA16
#undef PH_OPEN
#undef PH_CLOSE
#undef PH_CLOSE_F

#pragma unroll
  for (int m = 0; m < 8; ++m) {
#pragma unroll
    for (int j = 0; j < 4; ++j) {
      const int grow = bm0 + wr * 128 + m * 16 + (lane >> 4) * 4 + j;
      bf16* prow = P + (size_t)split * ((size_t)N_NODES * N_IN) + (size_t)grow * N_IN;
#pragma unroll
      for (int n = 0; n < 4; ++n) {
        const int gcol = bn0 + wc * 64 + n * 16 + (lane & 15);
        prow[gcol] = (bf16)acc[m][n][j];
      }
    }
  }
}

// ---- 128x128-tile GEMM (gemm2): out = tanh(A @ B^T + bias) ----
template<int KDIM>
__global__ __launch_bounds__(256, 2) void k_gemm(
    const bf16* __restrict__ A, const bf16* __restrict__ B,
    const float* __restrict__ bias, float* __restrict__ outf) {
  constexpr int NT = KDIM / 64;
  constexpr int NBLK = 256;
  __shared__ __attribute__((aligned(128))) char lds[2 * 32768];

  const int bid = blockIdx.x;
  const int logical = (bid & 7) * (NBLK / 8) + (bid >> 3);
  const int bm0 = (logical >> 2) * 128;
  const int bn0 = (logical & 3) * 128;

  const int tid = threadIdx.x;
  const int wid = tid >> 6;
  const int lane = tid & 63;
  const int wr = wid & 1, wc = wid >> 1;

  const int srow = tid >> 3;
  const int scol = ((tid & 7) ^ (srow & 7)) << 3;
  const size_t a_src = (size_t)(bm0 + srow) * KDIM + scol;
  const size_t b_src = (size_t)(bn0 + srow) * KDIM + scol;

  const int frow = lane & 15;
  const int fk = lane >> 4;
  const int swz = (lane & 7) << 4;
  const int a_row_byte = (wr * 64 + frow) * 128;
  const int b_row_byte = 16384 + (wc * 64 + frow) * 128;

  f32x4 acc[4][4] = {};

  auto stage = [&](int t) {
    char* lbase = lds + (t & 1) * 32768;
    const bf16* ag = A + a_src + (size_t)t * 64;
    const bf16* bg = B + b_src + (size_t)t * 64;
#pragma unroll
    for (int ch = 0; ch < 4; ++ch) {
      gload16(ag + (size_t)(ch * 32) * KDIM, lbase + ch * 4096 + wid * 1024);
      gload16(bg + (size_t)(ch * 32) * KDIM, lbase + 16384 + ch * 4096 + wid * 1024);
    }
  };

  auto compute = [&](int t) {
    const char* lbase = lds + (t & 1) * 32768;
#pragma unroll
    for (int kk = 0; kk < 2; ++kk) {
      const int colb = (kk * 64 + fk * 16) ^ swz;
      bf16x8 av[4], bv[4];
#pragma unroll
      for (int m = 0; m < 4; ++m)
        av[m] = *reinterpret_cast<const bf16x8*>(lbase + a_row_byte + m * 2048 + colb);
#pragma unroll
      for (int n = 0; n < 4; ++n)
        bv[n] = *reinterpret_cast<const bf16x8*>(lbase + b_row_byte + n * 2048 + colb);
#pragma unroll
      for (int m = 0; m < 4; ++m)
#pragma unroll
        for (int n = 0; n < 4; ++n)
          acc[m][n] = __builtin_amdgcn_mfma_f32_16x16x32_bf16(av[m], bv[n], acc[m][n], 0, 0, 0);
    }
  };

  stage(0);
#pragma unroll 1
  for (int t = 0; t < NT - 1; ++t) {
    stage(t + 1);
    WAITVM(8);
    BAR();
    compute(t);
    BAR();
  }
  WAITVM(0);
  BAR();
  compute(NT - 1);

#pragma unroll
  for (int m = 0; m < 4; ++m) {
#pragma unroll
    for (int j = 0; j < 4; ++j) {
      const int grow = bm0 + wr * 64 + m * 16 + (lane >> 4) * 4 + j;
      float* orow = outf + (size_t)grow * N_OUT;
#pragma unroll
      for (int n = 0; n < 4; ++n) {
        const int gcol = bn0 + wc * 64 + n * 16 + (lane & 15);
        float v = acc[m][n][j] + bias[gcol];
        v = fminf(fmaxf(v, -15.f), 15.f);
        const float e = __expf(2.f * v);
        orow[gcol] = (e - 1.f) / (e + 1.f);
      }
    }
  }
}

// ---- split-K reduce: Hm = bf16(d_i * (P0+P1+P2+P3)), bf16 partials ----
__global__ __launch_bounds__(256) void k_red(const bf16* __restrict__ P,
                                             const float* __restrict__ dv,
                                             bf16* __restrict__ Hm) {
  const int t = blockIdx.x * 256 + threadIdx.x;
  const int row = t >> 6;
  const int col = (t & 63) << 3;
  const size_t off = (size_t)row * N_IN + col;
  constexpr size_t S = (size_t)N_NODES * N_IN;
  const float d = dv[row];
  const bf16x8 p0 = *reinterpret_cast<const bf16x8*>(P + off);
  const bf16x8 p1 = *reinterpret_cast<const bf16x8*>(P + S + off);
  const bf16x8 p2 = *reinterpret_cast<const bf16x8*>(P + 2 * S + off);
  const bf16x8 p3 = *reinterpret_cast<const bf16x8*>(P + 3 * S + off);
  bf16x8 o;
#pragma unroll
  for (int e = 0; e < 8; ++e)
    o[e] = (bf16)(d * (((float)p0[e] + (float)p1[e]) + ((float)p2[e] + (float)p3[e])));
  *reinterpret_cast<bf16x8*>(Hm + off) = o;
}

extern "C" void kernel_launch(void* const* d_in, const int* in_sizes, int n_in,
                              void* d_out, int out_size, void* d_ws, size_t ws_size,
                              hipStream_t stream) {
  const float* H   = (const float*)d_in[0];
  const float* adj = (const float*)d_in[1];
  const float* W   = (const float*)d_in[2];
  const float* b   = (const float*)d_in[3];
  float* out = (float*)d_out;
  char* ws = (char*)d_ws;

  bf16*  adjb = (bf16*)(ws);                    // 8192*8192*2 = 134217728
  bf16*  Hst  = (bf16*)(ws + 134217728);        // 512*8192*2  = 8388608
  bf16*  Hm   = (bf16*)(ws + 142606336);        // 8192*512*2  = 8388608
  bf16*  Wb   = (bf16*)(ws + 150994944);        // 512*512*2   = 524288
  float* part = (float*)(ws + 151519232);       // 128*8192*4  = 4194304
  float* dv   = (float*)(ws + 155713536);       // 8192*4      = 32768
  bf16*  P    = (bf16*)(ws + 155746304);        // 4*8192*512*2 = 33554432

  // MEASUREMENT: colsum_cvt launched TWICE (idempotent). Marginal time vs
  // R7's 196.7us baseline = colsum_cvt's true duration.
  k_colsum_cvt<<<dim3(8, 128), 256, 0, stream>>>(adj, adjb, part);
  k_colsum_cvt<<<dim3(8, 128), 256, 0, stream>>>(adj, adjb, part);
  k_dvec_wcvt<<<288, 256, 0, stream>>>(part, dv, W, Wb);
  k_hst<<<dim3(128, 8), 256, 0, stream>>>(H, dv, Hst);
  // P[s] = (adj+I)b[:, s-quarter] @ Hst[s-quarter]^T   (split-K=4, bf16 partials)
  k_gemm256<8192, 4><<<256, 512, 0, stream>>>(adjb, Hst, P);
  // Hm = d_i*(P0+P1+P2+P3)
  k_red<<<2048, 256, 0, stream>>>(P, dv, Hm);
  // out = tanh(Hm @ W^T + b)
  k_gemm<512><<<256, 256, 0, stream>>>(Hm, Wb, b, out);
}

// Round 14
// 172.235 us; speedup vs baseline: 1.6777x; 1.6777x over previous
//
#include <hip/hip_runtime.h>
#include <hip/hip_bf16.h>

#define N_NODES 8192
#define N_IN 512
#define N_OUT 512

typedef __bf16 bf16;
typedef __bf16 bf16x4 __attribute__((ext_vector_type(4)));
typedef __bf16 bf16x8 __attribute__((ext_vector_type(8)));
typedef float f32x4 __attribute__((ext_vector_type(4)));

__device__ __forceinline__ void gload16(const void* g, void* l) {
  __builtin_amdgcn_global_load_lds((const __attribute__((address_space(1))) void*)g,
                                   (__attribute__((address_space(3))) void*)l, 16, 0, 0);
}

#define WAITVM(N) asm volatile("s_waitcnt vmcnt(" #N ")" ::: "memory")
#define BAR() do { asm volatile("" ::: "memory"); __builtin_amdgcn_s_barrier(); \
                   asm volatile("" ::: "memory"); } while (0)
#define SCHED0() __builtin_amdgcn_sched_barrier(0)
#define LGKM0() asm volatile("s_waitcnt lgkmcnt(0)" ::: "memory")

// ---- kernel 1 (REWRITTEN): colsum + cvt, 8 cols/thread, NT loads, 16B stores ----
// Measured R13: old version = 92.3us (4.2 TB/s). This version: 2x f32x4
// nontemporal loads (adj read-once; don't evict adjb from L3), bf16x8 16B
// stores (1KB/wave), 32-row loops, grid (4,256) = 1024 blocks = 4/CU.
__global__ __launch_bounds__(256) void k_colsum_cvt(const float* __restrict__ adj,
                                                    bf16* __restrict__ adjb,
                                                    float* __restrict__ partial) {
  const int tid  = threadIdx.x;
  const int col0 = blockIdx.x * 2048 + tid * 8;
  const int row0 = blockIdx.y * 32;
  float s[8] = {0.f, 0.f, 0.f, 0.f, 0.f, 0.f, 0.f, 0.f};
#pragma unroll 4
  for (int r = 0; r < 32; ++r) {
    const int row = row0 + r;
    const float* p = adj + (size_t)row * N_NODES + col0;
    const f32x4 v0 = __builtin_nontemporal_load(reinterpret_cast<const f32x4*>(p));
    const f32x4 v1 = __builtin_nontemporal_load(reinterpret_cast<const f32x4*>(p + 4));
    bf16x8 o;
#pragma unroll
    for (int e = 0; e < 4; ++e) {
      const float a = v0[e], bb = v1[e];
      s[e] += a; s[e + 4] += bb;
      // fold +I into adjb diagonal (degree uses ORIGINAL adj; +1 via dvec init)
      o[e]     = (bf16)(a  + ((row == col0 + e)     ? 1.f : 0.f));
      o[e + 4] = (bf16)(bb + ((row == col0 + 4 + e) ? 1.f : 0.f));
    }
    *reinterpret_cast<bf16x8*>(adjb + (size_t)row * N_NODES + col0) = o;
  }
  f32x4 p0 = { s[0], s[1], s[2], s[3] };
  f32x4 p1 = { s[4], s[5], s[6], s[7] };
  *reinterpret_cast<f32x4*>(partial + (size_t)blockIdx.y * N_NODES + col0) = p0;
  *reinterpret_cast<f32x4*>(partial + (size_t)blockIdx.y * N_NODES + col0 + 4) = p1;
}

// ---- kernel 2 (merged): blocks 0..31 -> d[j]=rsqrt(1+colsum, 256 partials);
// ---- blocks 32..287 -> W cvt ----
__global__ __launch_bounds__(256) void k_dvec_wcvt(const float* __restrict__ partial,
                                                   float* __restrict__ dv,
                                                   const float* __restrict__ W,
                                                   bf16* __restrict__ Wb) {
  const int b = blockIdx.x;
  const int tid = threadIdx.x;
  if (b < 32) {
    const int j = b * 256 + tid;
    float s = 1.0f;
#pragma unroll 8
    for (int p = 0; p < 256; ++p) s += partial[(size_t)p * N_NODES + j];
    dv[j] = rsqrtf(s);
  } else {
    const int i = ((b - 32) * 256 + tid) * 4;
    float4 v = *reinterpret_cast<const float4*>(W + i);
    bf16x4 o = { (bf16)v.x, (bf16)v.y, (bf16)v.z, (bf16)v.w };
    *reinterpret_cast<bf16x4*>(Wb + i) = o;
  }
}

// ---- kernel 3: Hst[k][j] = d[j]*H[j][k]  (transpose+scale, bf16; B^T layout for GEMM1) ----
__global__ __launch_bounds__(256) void k_hst(const float* __restrict__ H,
                                             const float* __restrict__ dv,
                                             bf16* __restrict__ Hst) {
  __shared__ float t[64][65];
  const int tid = threadIdx.x;
  const int j0 = blockIdx.x * 64;
  const int k0 = blockIdx.y * 64;
  const int rr = tid >> 4;
  const int cc = (tid & 15) * 4;
#pragma unroll
  for (int p = 0; p < 4; ++p) {
    const int r = p * 16 + rr;
    const float d = dv[j0 + r];
    float4 v = *reinterpret_cast<const float4*>(H + (size_t)(j0 + r) * N_IN + k0 + cc);
    t[r][cc + 0] = v.x * d; t[r][cc + 1] = v.y * d;
    t[r][cc + 2] = v.z * d; t[r][cc + 3] = v.w * d;
  }
  __syncthreads();
#pragma unroll
  for (int p = 0; p < 4; ++p) {
    const int kr = p * 16 + rr;
    bf16x4 o = { (bf16)t[cc + 0][kr], (bf16)t[cc + 1][kr],
                 (bf16)t[cc + 2][kr], (bf16)t[cc + 3][kr] };
    *reinterpret_cast<bf16x4*>(Hst + (size_t)(k0 + kr) * N_NODES + j0 + cc) = o;
  }
}

// ============ gemm1: 8-phase 256x256 machine (R7, measured ~59us/1165TF) ============
template<int KDIM, int NSPLIT>
__global__ __launch_bounds__(512, 2) void k_gemm256(
    const bf16* __restrict__ A, const bf16* __restrict__ B, bf16* __restrict__ P) {
  constexpr int KSEG = KDIM / NSPLIT;          // 2048
  constexpr int NT = KSEG / 64;                // 32 K-tiles
  constexpr int NIT = NT / 2;                  // 16 iters
  constexpr int NBLK = 64 * NSPLIT;            // 256
  __shared__ __attribute__((aligned(128))) char lds[2 * 65536];

  const int bid = blockIdx.x;
  const int l = (bid & 7) * (NBLK / 8) + (bid >> 3);
  const int split = l / 64;
  const int rem = l % 64;
  const int bm0 = (rem >> 1) * 256;
  const int bn0 = (rem & 1) * 256;

  const int tid = threadIdx.x;
  const int lane = tid & 63;
  const int wid = tid >> 6;
  const int wr = wid >> 2;
  const int wc = wid & 3;

  const int srow = tid >> 3;
  const int sslot = (tid & 7) ^ (srow & 7);
  const size_t koff = (size_t)split * KSEG;
  const int wuni = wid * 1024;

  auto GA = [&](int k, int h, int buf) {
    const bf16* g = A + (size_t)(bm0 + h * 128 + srow) * KDIM + koff + (size_t)k * 64 + sslot * 8;
    char* d = lds + buf * 65536 + h * 16384 + wuni;
    gload16(g, d);
    gload16(g + (size_t)64 * KDIM, d + 8192);
  };
  auto GB = [&](int k, int h, int buf) {
    const bf16* g = B + (size_t)(bn0 + h * 128 + srow) * KDIM + koff + (size_t)k * 64 + sslot * 8;
    char* d = lds + buf * 65536 + 32768 + h * 16384 + wuni;
    gload16(g, d);
    gload16(g + (size_t)64 * KDIM, d + 8192);
  };

  const int frow = lane & 15;
  const int fk = lane >> 4;
  const int e7 = lane & 7;
  const int sb0 = ((fk) ^ e7) << 4;
  const int sb1 = ((4 + fk) ^ e7) << 4;
  const int aBase = wr * 16384 + frow * 128;
  const int bBase = 32768 + (wc >> 1) * 16384 + ((wc & 1) * 64 + frow) * 128;

  f32x4 acc[8][4] = {};
  bf16x8 av[2][4], bv0[2][2], bv1[2][2];

#define LDA(BUF, MH)                                                          \
  do {                                                                        \
    const char* lb_ = lds + (BUF) * 65536;                                    \
    _Pragma("unroll") for (int m = 0; m < 4; ++m) {                           \
      av[0][m] = *(const bf16x8*)(lb_ + aBase + ((MH) * 4 + m) * 2048 + sb0); \
      av[1][m] = *(const bf16x8*)(lb_ + aBase + ((MH) * 4 + m) * 2048 + sb1); \
    }                                                                         \
  } while (0)
#define LDB(BUF, NH, BV)                                                      \
  do {                                                                        \
    const char* lb_ = lds + (BUF) * 65536;                                    \
    _Pragma("unroll") for (int n = 0; n < 2; ++n) {                           \
      BV[0][n] = *(const bf16x8*)(lb_ + bBase + ((NH) * 2 + n) * 2048 + sb0); \
      BV[1][n] = *(const bf16x8*)(lb_ + bBase + ((NH) * 2 + n) * 2048 + sb1); \
    }                                                                         \
  } while (0)
#define MFMA16(MH, NH, BV)                                                    \
  do {                                                                        \
    _Pragma("unroll") for (int kk = 0; kk < 2; ++kk)                          \
    _Pragma("unroll") for (int m = 0; m < 4; ++m)                             \
    _Pragma("unroll") for (int n = 0; n < 2; ++n)                             \
      acc[(MH) * 4 + m][(NH) * 2 + n] = __builtin_amdgcn_mfma_f32_16x16x32_bf16( \
          av[kk][m], BV[kk][n], acc[(MH) * 4 + m][(NH) * 2 + n], 0, 0, 0);    \
  } while (0)

#define PH_OPEN()  do { SCHED0(); __builtin_amdgcn_s_barrier(); LGKM0(); SCHED0(); \
                        __builtin_amdgcn_s_setprio(1); } while (0)
#define PH_CLOSE() do { __builtin_amdgcn_s_setprio(0); SCHED0(); \
                        __builtin_amdgcn_s_barrier(); SCHED0(); } while (0)
#define PH_CLOSE_F(WV) do { __builtin_amdgcn_s_setprio(0); SCHED0(); WV; \
                            __builtin_amdgcn_s_barrier(); SCHED0(); } while (0)

  GB(0, 0, 0); GB(0, 1, 0); GA(0, 0, 0); GA(0, 1, 0);
  GB(1, 0, 1); GB(1, 1, 1);
  WAITVM(4);
  BAR();

#pragma unroll 1
  for (int i = 0; i < NIT; ++i) {
    const int t = 2 * i;
    const bool s2 = (t + 2 < NT);
    const bool s3 = (t + 3 < NT);
    LDA(0, 0); LDB(0, 0, bv0);
    GA(t + 1, 0, 1);
    PH_OPEN(); MFMA16(0, 0, bv0); PH_CLOSE();
    LDB(0, 1, bv1);
    GA(t + 1, 1, 1);
    PH_OPEN(); MFMA16(0, 1, bv1); PH_CLOSE();
    LDA(0, 1);
    if (s2) GB(t + 2, 0, 0);
    PH_OPEN(); MFMA16(1, 1, bv1); PH_CLOSE();
    if (s2) GB(t + 2, 1, 0);
    PH_OPEN(); MFMA16(1, 0, bv0);
    if (s2) { PH_CLOSE_F(WAITVM(4)); } else { PH_CLOSE_F(WAITVM(0)); }
    LDA(1, 0); LDB(1, 0, bv0);
    if (s2) GA(t + 2, 0, 0);
    PH_OPEN(); MFMA16(0, 0, bv0); PH_CLOSE();
    LDB(1, 1, bv1);
    if (s2) GA(t + 2, 1, 0);
    PH_OPEN(); MFMA16(0, 1, bv1); PH_CLOSE();
    LDA(1, 1);
    if (s3) GB(t + 3, 0, 1);
    PH_OPEN(); MFMA16(1, 1, bv1); PH_CLOSE();
    if (s3) GB(t + 3, 1, 1);
    PH_OPEN(); MFMA16(1, 0, bv0);
    if (s3) { PH_CLOSE_F(WAITVM(4)); } else { PH_CLOSE_F(WAITVM(0)); }
  }
#undef LDA
#undef LDB
#undef MFMA16
#undef PH_OPEN
#undef PH_CLOSE
#undef PH_CLOSE_F

#pragma unroll
  for (int m = 0; m < 8; ++m) {
#pragma unroll
    for (int j = 0; j < 4; ++j) {
      const int grow = bm0 + wr * 128 + m * 16 + (lane >> 4) * 4 + j;
      bf16* prow = P + (size_t)split * ((size_t)N_NODES * N_IN) + (size_t)grow * N_IN;
#pragma unroll
      for (int n = 0; n < 4; ++n) {
        const int gcol = bn0 + wc * 64 + n * 16 + (lane & 15);
        prow[gcol] = (bf16)acc[m][n][j];
      }
    }
  }
}

// ---- 128x128-tile GEMM (gemm2): out = tanh(A @ B^T + bias) ----
template<int KDIM>
__global__ __launch_bounds__(256, 2) void k_gemm(
    const bf16* __restrict__ A, const bf16* __restrict__ B,
    const float* __restrict__ bias, float* __restrict__ outf) {
  constexpr int NT = KDIM / 64;
  constexpr int NBLK = 256;
  __shared__ __attribute__((aligned(128))) char lds[2 * 32768];

  const int bid = blockIdx.x;
  const int logical = (bid & 7) * (NBLK / 8) + (bid >> 3);
  const int bm0 = (logical >> 2) * 128;
  const int bn0 = (logical & 3) * 128;

  const int tid = threadIdx.x;
  const int wid = tid >> 6;
  const int lane = tid & 63;
  const int wr = wid & 1, wc = wid >> 1;

  const int srow = tid >> 3;
  const int scol = ((tid & 7) ^ (srow & 7)) << 3;
  const size_t a_src = (size_t)(bm0 + srow) * KDIM + scol;
  const size_t b_src = (size_t)(bn0 + srow) * KDIM + scol;

  const int frow = lane & 15;
  const int fk = lane >> 4;
  const int swz = (lane & 7) << 4;
  const int a_row_byte = (wr * 64 + frow) * 128;
  const int b_row_byte = 16384 + (wc * 64 + frow) * 128;

  f32x4 acc[4][4] = {};

  auto stage = [&](int t) {
    char* lbase = lds + (t & 1) * 32768;
    const bf16* ag = A + a_src + (size_t)t * 64;
    const bf16* bg = B + b_src + (size_t)t * 64;
#pragma unroll
    for (int ch = 0; ch < 4; ++ch) {
      gload16(ag + (size_t)(ch * 32) * KDIM, lbase + ch * 4096 + wid * 1024);
      gload16(bg + (size_t)(ch * 32) * KDIM, lbase + 16384 + ch * 4096 + wid * 1024);
    }
  };

  auto compute = [&](int t) {
    const char* lbase = lds + (t & 1) * 32768;
#pragma unroll
    for (int kk = 0; kk < 2; ++kk) {
      const int colb = (kk * 64 + fk * 16) ^ swz;
      bf16x8 av[4], bv[4];
#pragma unroll
      for (int m = 0; m < 4; ++m)
        av[m] = *reinterpret_cast<const bf16x8*>(lbase + a_row_byte + m * 2048 + colb);
#pragma unroll
      for (int n = 0; n < 4; ++n)
        bv[n] = *reinterpret_cast<const bf16x8*>(lbase + b_row_byte + n * 2048 + colb);
#pragma unroll
      for (int m = 0; m < 4; ++m)
#pragma unroll
        for (int n = 0; n < 4; ++n)
          acc[m][n] = __builtin_amdgcn_mfma_f32_16x16x32_bf16(av[m], bv[n], acc[m][n], 0, 0, 0);
    }
  };

  stage(0);
#pragma unroll 1
  for (int t = 0; t < NT - 1; ++t) {
    stage(t + 1);
    WAITVM(8);
    BAR();
    compute(t);
    BAR();
  }
  WAITVM(0);
  BAR();
  compute(NT - 1);

#pragma unroll
  for (int m = 0; m < 4; ++m) {
#pragma unroll
    for (int j = 0; j < 4; ++j) {
      const int grow = bm0 + wr * 64 + m * 16 + (lane >> 4) * 4 + j;
      float* orow = outf + (size_t)grow * N_OUT;
#pragma unroll
      for (int n = 0; n < 4; ++n) {
        const int gcol = bn0 + wc * 64 + n * 16 + (lane & 15);
        float v = acc[m][n][j] + bias[gcol];
        v = fminf(fmaxf(v, -15.f), 15.f);
        const float e = __expf(2.f * v);
        orow[gcol] = (e - 1.f) / (e + 1.f);
      }
    }
  }
}

// ---- split-K reduce: Hm = bf16(d_i * (P0+P1+P2+P3)), bf16 partials ----
__global__ __launch_bounds__(256) void k_red(const bf16* __restrict__ P,
                                             const float* __restrict__ dv,
                                             bf16* __restrict__ Hm) {
  const int t = blockIdx.x * 256 + threadIdx.x;
  const int row = t >> 6;
  const int col = (t & 63) << 3;
  const size_t off = (size_t)row * N_IN + col;
  constexpr size_t S = (size_t)N_NODES * N_IN;
  const float d = dv[row];
  const bf16x8 p0 = *reinterpret_cast<const bf16x8*>(P + off);
  const bf16x8 p1 = *reinterpret_cast<const bf16x8*>(P + S + off);
  const bf16x8 p2 = *reinterpret_cast<const bf16x8*>(P + 2 * S + off);
  const bf16x8 p3 = *reinterpret_cast<const bf16x8*>(P + 3 * S + off);
  bf16x8 o;
#pragma unroll
  for (int e = 0; e < 8; ++e)
    o[e] = (bf16)(d * (((float)p0[e] + (float)p1[e]) + ((float)p2[e] + (float)p3[e])));
  *reinterpret_cast<bf16x8*>(Hm + off) = o;
}

extern "C" void kernel_launch(void* const* d_in, const int* in_sizes, int n_in,
                              void* d_out, int out_size, void* d_ws, size_t ws_size,
                              hipStream_t stream) {
  const float* H   = (const float*)d_in[0];
  const float* adj = (const float*)d_in[1];
  const float* W   = (const float*)d_in[2];
  const float* b   = (const float*)d_in[3];
  float* out = (float*)d_out;
  char* ws = (char*)d_ws;

  bf16*  adjb = (bf16*)(ws);                    // 8192*8192*2 = 134217728
  bf16*  Hst  = (bf16*)(ws + 134217728);        // 512*8192*2  = 8388608
  bf16*  Hm   = (bf16*)(ws + 142606336);        // 8192*512*2  = 8388608
  bf16*  Wb   = (bf16*)(ws + 150994944);        // 512*512*2   = 524288
  float* part = (float*)(ws + 151519232);       // 256*8192*4  = 8388608
  float* dv   = (float*)(ws + 159907840);       // 8192*4      = 32768
  bf16*  P    = (bf16*)(ws + 159940608);        // 4*8192*512*2 = 33554432

  k_colsum_cvt<<<dim3(4, 256), 256, 0, stream>>>(adj, adjb, part);
  k_dvec_wcvt<<<288, 256, 0, stream>>>(part, dv, W, Wb);
  k_hst<<<dim3(128, 8), 256, 0, stream>>>(H, dv, Hst);
  // P[s] = (adj+I)b[:, s-quarter] @ Hst[s-quarter]^T   (split-K=4, bf16 partials)
  k_gemm256<8192, 4><<<256, 512, 0, stream>>>(adjb, Hst, P);
  // Hm = d_i*(P0+P1+P2+P3)
  k_red<<<2048, 256, 0, stream>>>(P, dv, Hm);
  // out = tanh(Hm @ W^T + b)
  k_gemm<512><<<256, 256, 0, stream>>>(Hm, Wb, b, out);
}